// Round 1
// baseline (654.191 us; speedup 1.0000x reference)
//
#include <hip/hip_runtime.h>
#include <stdint.h>

// Conv2d(64->128, 3x3, VALID) + BN(inference) + scale, fused, via implicit-GEMM
// bf16 MFMA. M=128 out-channels, N=508032 pixels, K=576 (=64*9).
// Block tile 128x128x32, 256 threads = 4 waves (2x2), wave tile 64x64 via
// 4x4 mfma_f32_16x16x32_bf16. 508032 = 3969*128 exactly -> no bounds checks.

typedef __attribute__((ext_vector_type(8))) short bf16x8;   // 8 bf16 in 4 VGPRs
typedef __attribute__((ext_vector_type(4))) float f32x4;

#define C_IN   64
#define HW     128      // input H and W
#define K_OUT  128
#define QO     126      // output Q (and P)
#define PQ     15876    // 126*126
#define KTOT   576      // 64*9
#define BM     128
#define BN     128
#define BK     32
#define LSTR   34       // LDS row stride in bf16 (68 B = 17 words; gcd(17,32)=1)

__device__ __forceinline__ uint32_t f2bf(float f) {
    // round-to-nearest-even bf16 (finite inputs)
    uint32_t u = __builtin_bit_cast(uint32_t, f);
    return (u + 0x7FFFu + ((u >> 16) & 1u)) >> 16;
}
__device__ __forceinline__ uint32_t pack2(float a, float b) {
    return f2bf(a) | (f2bf(b) << 16);
}

__global__ __launch_bounds__(256, 2)
void conv_bn_scale_kernel(const float* __restrict__ x,
                          const float* __restrict__ Wt,
                          const float* __restrict__ Bb,
                          const float* __restrict__ rmean,
                          const float* __restrict__ rvar,
                          const float* __restrict__ bnw,
                          const float* __restrict__ bnb,
                          const float* __restrict__ scl,
                          float* __restrict__ out)
{
    __shared__ unsigned short As[BM * LSTR];   // weights  [m][k] k-contig
    __shared__ unsigned short Bs[BN * LSTR];   // im2col   [pix][k] k-contig
    __shared__ float alpha_s[K_OUT];
    __shared__ float beta_s[K_OUT];

    const int tid = threadIdx.x;

    // Fold BN+bias+scale into per-channel alpha/beta:
    // out = conv*alpha + beta; alpha = inv_std*bnw*scale,
    // beta = (B-mean)*alpha + bnb*scale
    if (tid < K_OUT) {
        float sc = scl[0];
        float inv_std = rsqrtf(rvar[tid] + 1e-5f);
        float a = inv_std * bnw[tid] * sc;
        alpha_s[tid] = a;
        beta_s[tid] = (Bb[tid] - rmean[tid]) * a + bnb[tid] * sc;
    }

    const int lane = tid & 63;
    const int wid  = tid >> 6;
    const int wm   = wid >> 1;      // wave row (m): 0..1
    const int wn   = wid & 1;       // wave col (n): 0..1
    const int quad = lane >> 4;     // 0..3
    const int l16  = lane & 15;

    // ---- B-staging pixel for this thread (fixed for whole kernel)
    const int spix = tid & 127;
    const int jst  = blockIdx.x * BN + spix;        // global pixel id
    const int n_s  = jst / PQ;
    const int rem  = jst - n_s * PQ;
    const int p_s  = rem / QO;
    const int q_s  = rem - p_s * QO;
    // x[n][c][p+r][q+s]; base at c=0,r=0,s=0. VALID conv -> always in-bounds.
    const float* xb = x + ((n_s * C_IN) * HW + p_s) * HW + q_s;
    const int khalf = tid >> 7;     // 0/1: which kk-pair this thread stages

    f32x4 acc[4][4];
    #pragma unroll
    for (int i = 0; i < 4; ++i)
        #pragma unroll
        for (int j = 0; j < 4; ++j)
            acc[i][j] = (f32x4){0.f, 0.f, 0.f, 0.f};

    for (int k0 = 0; k0 < KTOT; k0 += BK) {
        __syncthreads();

        // ---- stage A: W[128][k0..k0+31] as bf16 pairs (coalesced float2)
        #pragma unroll
        for (int it = 0; it < 8; ++it) {
            int pair = it * 256 + tid;
            int mm   = pair >> 4;            // 0..127
            int kk   = (pair & 15) * 2;      // 0,2,..,30
            float2 wv = *(const float2*)(Wt + mm * KTOT + k0 + kk);
            *(uint32_t*)&As[mm * LSTR + kk] = pack2(wv.x, wv.y);
        }

        // ---- stage B: im2col gather, transpose-on-write into LDS
        #pragma unroll
        for (int it = 0; it < 8; ++it) {
            int pairidx = it * 2 + khalf;    // 0..15
            int kk  = k0 + pairidx * 2;
            int c0  = kk / 9;  int t0 = kk - c0 * 9;
            int r0  = t0 / 3;  int s0 = t0 - r0 * 3;
            int kk1 = kk + 1;
            int c1  = kk1 / 9; int t1 = kk1 - c1 * 9;
            int r1  = t1 / 3;  int s1 = t1 - r1 * 3;
            float v0 = xb[(c0 * HW + r0) * HW + s0];   // coalesced along pix
            float v1 = xb[(c1 * HW + r1) * HW + s1];
            *(uint32_t*)&Bs[spix * LSTR + pairidx * 2] = pack2(v0, v1);
        }

        __syncthreads();

        // ---- fragments + 16 MFMAs per wave
        bf16x8 af[4], bfr[4];
        #pragma unroll
        for (int ms = 0; ms < 4; ++ms) {
            const uint32_t* sp =
                (const uint32_t*)&As[(wm * 64 + ms * 16 + l16) * LSTR] + quad * 4;
            union { uint32_t u[4]; bf16x8 v; } tmp;
            tmp.u[0] = sp[0]; tmp.u[1] = sp[1]; tmp.u[2] = sp[2]; tmp.u[3] = sp[3];
            af[ms] = tmp.v;
        }
        #pragma unroll
        for (int ns = 0; ns < 4; ++ns) {
            const uint32_t* sp =
                (const uint32_t*)&Bs[(wn * 64 + ns * 16 + l16) * LSTR] + quad * 4;
            union { uint32_t u[4]; bf16x8 v; } tmp;
            tmp.u[0] = sp[0]; tmp.u[1] = sp[1]; tmp.u[2] = sp[2]; tmp.u[3] = sp[3];
            bfr[ns] = tmp.v;
        }
        #pragma unroll
        for (int ms = 0; ms < 4; ++ms)
            #pragma unroll
            for (int ns = 0; ns < 4; ++ns)
                acc[ms][ns] = __builtin_amdgcn_mfma_f32_16x16x32_bf16(
                    af[ms], bfr[ns], acc[ms][ns], 0, 0, 0);
    }

    // ---- epilogue: out[n][k][p][q] = acc*alpha[k] + beta[k]
    // C/D layout: col(pixel) = lane&15, row(channel) = quad*4 + reg
    #pragma unroll
    for (int ns = 0; ns < 4; ++ns) {
        int j  = blockIdx.x * BN + wn * 64 + ns * 16 + l16;  // global pixel
        int nb = j / PQ;
        int obase = j + PQ * (nb * (K_OUT - 1));             // + k*PQ per chan
        #pragma unroll
        for (int ms = 0; ms < 4; ++ms) {
            int kb = wm * 64 + ms * 16 + quad * 4;
            #pragma unroll
            for (int r = 0; r < 4; ++r) {
                int k = kb + r;
                out[obase + k * PQ] = acc[ms][ns][r] * alpha_s[k] + beta_s[k];
            }
        }
    }
}

extern "C" void kernel_launch(void* const* d_in, const int* in_sizes, int n_in,
                              void* d_out, int out_size, void* d_ws, size_t ws_size,
                              hipStream_t stream) {
    const float* x     = (const float*)d_in[0];
    const float* Wt    = (const float*)d_in[1];
    const float* Bb    = (const float*)d_in[2];
    const float* rmean = (const float*)d_in[3];
    const float* rvar  = (const float*)d_in[4];
    const float* bnw   = (const float*)d_in[5];
    const float* bnb   = (const float*)d_in[6];
    const float* scl   = (const float*)d_in[7];
    float* out = (float*)d_out;

    const int npix = 32 * PQ;          // 508032
    const int grid = npix / BN;        // 3969 blocks, no remainder
    conv_bn_scale_kernel<<<grid, 256, 0, stream>>>(
        x, Wt, Bb, rmean, rvar, bnw, bnb, scl, out);
}

// Round 2
// 630.554 us; speedup vs baseline: 1.0375x; 1.0375x over previous
//
#include <hip/hip_runtime.h>
#include <stdint.h>

// Conv2d(64->128,3x3,VALID)+BN+scale via register-direct implicit-GEMM bf16 MFMA.
// Pre-pass 1: x NCHW f32 -> xt NHWC bf16 (d_ws). Pre-pass 2: W -> bf16 [o][rs][c],
// fold BN into alpha/beta. Main: no LDS, no barriers; A/B fragments loaded
// directly from global as 16B dwordx4 (fully coalesced, L1/L2-hot).

typedef __attribute__((ext_vector_type(8))) short bf16x8;   // 8 bf16, 4 VGPRs
typedef __attribute__((ext_vector_type(4))) float f32x4;

#define C_IN   64
#define HW     128
#define K_OUT  128
#define QO     126
#define PQ     15876        // 126*126
#define KTOT   576          // 9*64, k = (r*3+s)*64 + c
#define BN_T   128          // block pixel tile

__device__ __forceinline__ uint32_t f2bf(float f) {
    uint32_t u = __builtin_bit_cast(uint32_t, f);
    return (u + 0x7FFFu + ((u >> 16) & 1u)) >> 16;   // RNE
}
__device__ __forceinline__ uint32_t pack2(float a, float b) {
    return f2bf(a) | (f2bf(b) << 16);
}

// ---------- pre-pass 1: x NCHW f32 -> xt NHWC bf16 ----------
__global__ __launch_bounds__(256)
void xpose_kernel(const float* __restrict__ x, uint32_t* __restrict__ xt) {
    __shared__ float tile[HW][C_IN + 1];      // [w][c], pad -> conflict-free
    const int n   = blockIdx.x >> 7;
    const int h   = blockIdx.x & 127;
    const int tid = threadIdx.x;
    #pragma unroll
    for (int it = 0; it < 32; ++it) {
        int idx = it * 256 + tid;
        int c = idx >> 7, w = idx & 127;
        tile[w][c] = x[((n * C_IN + c) * HW + h) * HW + w];   // coalesced over w
    }
    __syncthreads();
    #pragma unroll
    for (int it = 0; it < 16; ++it) {
        int idx = it * 256 + tid;
        int w = idx >> 5, cp = idx & 31;
        xt[((n * HW + h) * HW + w) * 32 + cp] =
            pack2(tile[w][cp * 2], tile[w][cp * 2 + 1]);      // coalesced write
    }
}

// ---------- pre-pass 2: W -> bf16 [o][tap][c]; alpha/beta ----------
__global__ __launch_bounds__(64)
void wprep_kernel(const float* __restrict__ W, const float* __restrict__ Bb,
                  const float* __restrict__ rmean, const float* __restrict__ rvar,
                  const float* __restrict__ bnw, const float* __restrict__ bnb,
                  const float* __restrict__ scl,
                  unsigned short* __restrict__ Wb,
                  float* __restrict__ alpha, float* __restrict__ beta) {
    const int o = blockIdx.x;       // out-channel
    const int c = threadIdx.x;      // in-channel
    #pragma unroll
    for (int t = 0; t < 9; ++t)
        Wb[(o * 9 + t) * 64 + c] = (unsigned short)f2bf(W[(o * 64 + c) * 9 + t]);
    if (c == 0) {
        float sc = scl[0];
        float a = rsqrtf(rvar[o] + 1e-5f) * bnw[o] * sc;
        alpha[o] = a;
        beta[o]  = (Bb[o] - rmean[o]) * a + bnb[o] * sc;
    }
}

// ---------- main: 128x128 block tile, 4 waves 2x2, wave 64x64 ----------
__global__ __launch_bounds__(256, 3)
void conv_main_kernel(const char* __restrict__ xt, const char* __restrict__ wb,
                      const float* __restrict__ alpha, const float* __restrict__ beta,
                      float* __restrict__ out) {
    const int tid  = threadIdx.x;
    const int lane = tid & 63;
    const int wid  = tid >> 6;
    const int wm   = wid >> 1, wn = wid & 1;
    const int quad = lane >> 4, l16 = lane & 15;

    // A-fragment voffsets: Wb[m][k], lane m=l16, k=quad*8 (+cc*32 via imm)
    int vA[4];
    #pragma unroll
    for (int ms = 0; ms < 4; ++ms)
        vA[ms] = ((wm * 64 + ms * 16 + l16) * KTOT + quad * 8) * 2;

    // B-fragment voffsets per (ns, r): xt[n][p+r][q+s][c], lane pix=l16, k=quad*8
    int vB[4][3];
    #pragma unroll
    for (int ns = 0; ns < 4; ++ns) {
        int j = blockIdx.x * BN_T + wn * 64 + ns * 16 + l16;
        int n = j / PQ;  int rem = j - n * PQ;
        int p = rem / QO; int q = rem - p * QO;
        #pragma unroll
        for (int r = 0; r < 3; ++r)
            vB[ns][r] = (((n * HW + p + r) * HW + q) * C_IN + quad * 8) * 2;
    }

    f32x4 acc[4][4];
    #pragma unroll
    for (int i = 0; i < 4; ++i)
        #pragma unroll
        for (int j = 0; j < 4; ++j)
            acc[i][j] = (f32x4){0.f, 0.f, 0.f, 0.f};

    bf16x8 Af[2][4], Bf[2][4];
    // prefetch chunk 0 (tap 0: r=0,s=0,c0=0)
    #pragma unroll
    for (int ms = 0; ms < 4; ++ms)
        Af[0][ms] = *(const bf16x8*)(wb + vA[ms]);
    #pragma unroll
    for (int ns = 0; ns < 4; ++ns)
        Bf[0][ns] = *(const bf16x8*)(xt + vB[ns][0]);

    #pragma unroll
    for (int cc = 0; cc < 18; ++cc) {
        const int cur = cc & 1, nxt = cur ^ 1;
        if (cc < 17) {
            const int c2  = cc + 1;
            const int tap = c2 >> 1;
            const int r   = tap / 3;
            const int s   = tap - r * 3;
            const int boff = s * C_IN * 2 + (c2 & 1) * 64;   // imm <= 320
            #pragma unroll
            for (int ms = 0; ms < 4; ++ms)
                Af[nxt][ms] = *(const bf16x8*)(wb + vA[ms] + c2 * 64);
            #pragma unroll
            for (int ns = 0; ns < 4; ++ns)
                Bf[nxt][ns] = *(const bf16x8*)(xt + vB[ns][r] + boff);
        }
        #pragma unroll
        for (int ms = 0; ms < 4; ++ms)
            #pragma unroll
            for (int ns = 0; ns < 4; ++ns)
                acc[ms][ns] = __builtin_amdgcn_mfma_f32_16x16x32_bf16(
                    Af[cur][ms], Bf[cur][ns], acc[ms][ns], 0, 0, 0);
    }

    // epilogue: out[n][k][p][q] = acc*alpha[k] + beta[k]
    // C/D layout: col(pixel)=lane&15, row(channel)=quad*4+reg
    #pragma unroll
    for (int ns = 0; ns < 4; ++ns) {
        int j  = blockIdx.x * BN_T + wn * 64 + ns * 16 + l16;
        int nb = j / PQ;
        int obase = j + PQ * (nb * (K_OUT - 1));
        #pragma unroll
        for (int ms = 0; ms < 4; ++ms) {
            int kb = wm * 64 + ms * 16 + quad * 4;
            f32x4 al = *(const f32x4*)(alpha + kb);
            f32x4 be = *(const f32x4*)(beta + kb);
            #pragma unroll
            for (int r = 0; r < 4; ++r)
                out[obase + (kb + r) * PQ] = acc[ms][ns][r] * al[r] + be[r];
        }
    }
}

extern "C" void kernel_launch(void* const* d_in, const int* in_sizes, int n_in,
                              void* d_out, int out_size, void* d_ws, size_t ws_size,
                              hipStream_t stream) {
    const float* x     = (const float*)d_in[0];
    const float* Wt    = (const float*)d_in[1];
    const float* Bb    = (const float*)d_in[2];
    const float* rmean = (const float*)d_in[3];
    const float* rvar  = (const float*)d_in[4];
    const float* bnw   = (const float*)d_in[5];
    const float* bnb   = (const float*)d_in[6];
    const float* scl   = (const float*)d_in[7];
    float* out = (float*)d_out;

    char* ws = (char*)d_ws;
    uint32_t*       xt    = (uint32_t*)ws;                       // 64 MiB NHWC bf16
    unsigned short* Wb    = (unsigned short*)(ws + 67108864);    // 147456 B
    float*          alpha = (float*)(ws + 67108864 + 147456);    // 512 B
    float*          beta  = alpha + 128;                         // 512 B

    xpose_kernel<<<32 * 128, 256, 0, stream>>>(x, xt);
    wprep_kernel<<<128, 64, 0, stream>>>(Wt, Bb, rmean, rvar, bnw, bnb, scl,
                                         Wb, alpha, beta);
    const int grid = (32 * PQ) / BN_T;   // 3969, exact
    conv_main_kernel<<<grid, 256, 0, stream>>>((const char*)xt, (const char*)Wb,
                                               alpha, beta, out);
}